// Round 10
// baseline (213.464 us; speedup 1.0000x reference)
//
#include <hip/hip_runtime.h>
#include <hip/hip_bf16.h>
#include <stdint.h>

typedef unsigned short u16;
typedef __attribute__((ext_vector_type(8))) short short8;
typedef __attribute__((ext_vector_type(4))) float float4v;
typedef __attribute__((ext_vector_type(2))) _Float16 v2h;

// RNE float->bf16
__device__ __forceinline__ u16 f2bf(float x) {
    union { float f; unsigned int u; } v; v.f = x;
    unsigned int r = v.u + 0x7fffu + ((v.u >> 16) & 1u);
    return (u16)(r >> 16);
}

__device__ __forceinline__ void ld_g2l16(const void* g, void* l) {
    __builtin_amdgcn_global_load_lds(
        (const __attribute__((address_space(1))) void*)g,
        (__attribute__((address_space(3))) void*)l, 16, 0, 0);
}

// packed fp16 dot-accumulate: s += a.x*b.x + a.y*b.y (fp32 acc)
__device__ __forceinline__ float dot2acc(v2h a, v2h b, float s) {
#if __has_builtin(__builtin_amdgcn_fdot2)
    return __builtin_amdgcn_fdot2(a, b, s, false);
#else
    return fmaf((float)a[0], (float)b[0], fmaf((float)a[1], (float)b[1], s));
#endif
}

// ---------------- Pass 0: pack W1 into B-frag layout (tiny) ----------------------
// W1pack[kc][t][lane][j] = W1[kc*32 + (lane>>4)*8 + j][t*16 + (lane&15)]
__global__ __launch_bounds__(256) void w1_pack(
    const float* __restrict__ W1, u16* __restrict__ w1p)
{
    int w = blockIdx.x * 256 + threadIdx.x;   // 0..4095
    int lanep = w & 63, t = (w >> 6) & 7, kc = w >> 9;
    short8 o;
#pragma unroll
    for (int j = 0; j < 8; ++j) {
        int k = kc * 32 + (lanep >> 4) * 8 + j;
        int n = t * 16 + (lanep & 15);
        o[j] = (short)f2bf(W1[k * 128 + n]);
    }
    *(short8*)(w1p + (size_t)w * 8) = o;
}

// ---------------- Pass 1: dense GEMMs U = zs@W1a + b1, V = zt@W1b (fp16 out) -----
// 64-row x 128-col tiles, K=128 single shot. LDS = 16KB A + 32KB B = 48KB ->
// 3 blocks/CU, 2345 blocks: 2x the staging overlap of the 128-row version.
// A staged fp32->bf16 through VGPRs into LDS with per-row XOR chunk swizzle
// (phys chunk q = c ^ (r&15)): MFMA-side ds_read_b128 is 2-way (free).
// B = W1 half in frag layout from w1p. Streaming z reads are nontemporal.
__global__ __launch_bounds__(256) void uv_gemm(
    const float* __restrict__ zs, const float* __restrict__ zt,
    const u16* __restrict__ w1p, const float* __restrict__ b1,
    u16* __restrict__ U, u16* __restrict__ V,
    int M1, int M2, int nU)
{
    __shared__ u16 Alds[8192];    // 16 KB: 64 rows x 128 K (swizzled 16B chunks)
    __shared__ u16 Blds[16384];   // 32 KB: 32 frags of this W1 half

    const int tid = threadIdx.x, wave = tid >> 6, lane = tid & 63;
    const int m15 = lane & 15, quad = lane >> 4;
    const bool isV = (int)blockIdx.x >= nU;
    const float* zsrc = isV ? zt : zs;
    u16* dst = isV ? V : U;
    const int row0 = (isV ? ((int)blockIdx.x - nU) : (int)blockIdx.x) * 64;
    const int M = isV ? M2 : M1;
    const int nrows = (M - row0) < 64 ? (M - row0) : 64;

    // stage B half (32 KB flat): frag f local = kc*8+t
    const u16* wsrc = w1p + (isV ? 16384 : 0);
#pragma unroll
    for (int it = 0; it < 8; ++it) {
        int off = (wave * 8 + it) * 1024;
        ld_g2l16((const char*)wsrc + off + lane * 16, (char*)Blds + off);
    }

    // stage A: 64 rows x 16 chunks(16B); 4 entries/thread
#pragma unroll
    for (int it = 0; it < 4; ++it) {
        int r = it * 16 + wave * 4 + (lane >> 4);
        int q = lane & 15;
        int c = q ^ (r & 15);                     // logical chunk to fetch
        int rr = r < nrows ? r : (nrows - 1);
        const float4v* src = (const float4v*)(zsrc + (size_t)(row0 + rr) * 128 + c * 8);
        float4v x = __builtin_nontemporal_load(src);
        float4v y = __builtin_nontemporal_load(src + 1);
        short8 o;
        o[0] = (short)f2bf(x[0]); o[1] = (short)f2bf(x[1]);
        o[2] = (short)f2bf(x[2]); o[3] = (short)f2bf(x[3]);
        o[4] = (short)f2bf(y[0]); o[5] = (short)f2bf(y[1]);
        o[6] = (short)f2bf(y[2]); o[7] = (short)f2bf(y[3]);
        *(short8*)((char*)Alds + r * 256 + q * 16) = o;
    }

    __builtin_amdgcn_s_waitcnt(0);
    __syncthreads();

    // MFMA: wave owns rows [wave*16, +16) x all 128 n
    float4v acc[8];
#pragma unroll
    for (int b = 0; b < 8; ++b)
        acc[b] = (float4v){0.f, 0.f, 0.f, 0.f};

#pragma unroll
    for (int kc = 0; kc < 4; ++kc) {
        int r = wave * 16 + m15;
        int c = kc * 4 + quad;
        int q = c ^ (r & 15);
        short8 Af = *(const short8*)((const char*)Alds + r * 256 + q * 16);
#pragma unroll
        for (int t = 0; t < 8; ++t) {
            short8 Bf = *(const short8*)((const char*)Blds + (kc * 8 + t) * 1024 + lane * 16);
            acc[t] = __builtin_amdgcn_mfma_f32_16x16x32_bf16(Af, Bf, acc[t], 0, 0, 0);
        }
    }

    // epilogue: +b1 (U only), round to fp16, store. C/D: col=t*16+m15, row=quad*4+r
#pragma unroll
    for (int t = 0; t < 8; ++t) {
        float bv = isV ? 0.f : b1[t * 16 + m15];
#pragma unroll
        for (int r = 0; r < 4; ++r) {
            int rr = wave * 16 + quad * 4 + r;
            if (rr < nrows) {
                _Float16 h = (_Float16)(acc[t][r] + bv);
                union { _Float16 h; u16 u; } cv; cv.h = h;
                dst[(size_t)(row0 + rr) * 128 + t * 16 + m15] = cv.u;
            }
        }
    }
}

// ---------------- Pass 2: streaming edge decode: relu(U[row]+V[col]).W2 + b2 -----
// 16 lanes per edge (lane m15 owns features [m15*8, m15*8+8)); 128 edges/block.
// All 16 gathers (8 edges x U,V) issued back-to-back per thread, then packed
// fp16 math: v_pk_add_f16 + v_pk_max_f16 + v_dot2_f32_f16 (fp32 accumulate).
// Index loads + output stores nontemporal (single-use; keep L2 for U/V reuse).
// MEASURED WALL (R6/R8): 68 us at ~7.5 TB/s effective gather (225 MB L2-miss
// at the ~3.5 TB/s fabric ceiling). VALU-neutral changes don't move it.
__global__ __launch_bounds__(256) void edge_out(
    const u16* __restrict__ U, const u16* __restrict__ V,
    const int* __restrict__ row, const int* __restrict__ col,
    const float* __restrict__ W2, const float* __restrict__ b2,
    float* __restrict__ out, int E)
{
    const int tid = threadIdx.x, m15 = tid & 15, g = tid >> 4;  // 16 groups
    v2h w2h[4];
#pragma unroll
    for (int j = 0; j < 4; ++j) {
        w2h[j][0] = (_Float16)W2[m15 * 8 + 2 * j];
        w2h[j][1] = (_Float16)W2[m15 * 8 + 2 * j + 1];
    }
    const float b2v = b2[0];
    const v2h zero2 = (v2h){(_Float16)0.f, (_Float16)0.f};
    const int e0 = blockIdx.x * 128;

    int ee[8];
#pragma unroll
    for (int it = 0; it < 8; ++it) {
        int e = e0 + it * 16 + g;
        ee[it] = e < E ? e : E - 1;
    }

    uint4 uu[8], vv[8];
#pragma unroll
    for (int it = 0; it < 8; ++it) {
        int ri = __builtin_nontemporal_load(row + ee[it]);
        int ci = __builtin_nontemporal_load(col + ee[it]);
        uu[it] = *(const uint4*)(U + (size_t)(unsigned)ri * 128 + m15 * 8);
        vv[it] = *(const uint4*)(V + (size_t)(unsigned)ci * 128 + m15 * 8);
    }

#pragma unroll
    for (int it = 0; it < 8; ++it) {
        float s = 0.f;
        const v2h* uw = (const v2h*)&uu[it];
        const v2h* vw = (const v2h*)&vv[it];
#pragma unroll
        for (int j = 0; j < 4; ++j) {
            v2h h = uw[j] + vw[j];                       // v_pk_add_f16
            h = __builtin_elementwise_max(h, zero2);     // v_pk_max_f16 (relu)
            s = dot2acc(h, w2h[j], s);                   // v_dot2_f32_f16
        }
        s += __shfl_xor(s, 1);
        s += __shfl_xor(s, 2);
        s += __shfl_xor(s, 4);
        s += __shfl_xor(s, 8);
        int e = e0 + it * 16 + g;
        if (m15 == 0 && e < E) __builtin_nontemporal_store(s + b2v, out + e);
    }
}

// ---------------- Fallback (fp32, slow but correct) if workspace too small -------
__global__ __launch_bounds__(256) void edge_mlp_naive(
    const float* __restrict__ zs, const float* __restrict__ zt,
    const int* __restrict__ row, const int* __restrict__ col,
    const float* __restrict__ W1, const float* __restrict__ b1,
    const float* __restrict__ W2, const float* __restrict__ b2,
    float* __restrict__ out, int E)
{
    __shared__ float zr[4][256];
    int wave = threadIdx.x >> 6, lane = threadIdx.x & 63;
    int e = blockIdx.x * 4 + wave;
    int ec = e < E ? e : E - 1;
    const float* a = zs + (size_t)row[ec] * 128;
    const float* bb = zt + (size_t)col[ec] * 128;
    zr[wave][lane] = a[lane];
    zr[wave][64 + lane] = a[64 + lane];
    zr[wave][128 + lane] = bb[lane];
    zr[wave][192 + lane] = bb[64 + lane];
    __syncthreads();
    float h0 = b1[lane], h1 = b1[64 + lane];
    for (int k = 0; k < 256; ++k) {
        float zk = zr[wave][k];
        h0 = fmaf(zk, W1[k * 128 + lane], h0);
        h1 = fmaf(zk, W1[k * 128 + 64 + lane], h1);
    }
    h0 = h0 > 0.f ? h0 : 0.f;
    h1 = h1 > 0.f ? h1 : 0.f;
    float s = fmaf(h0, W2[lane], h1 * W2[64 + lane]);
    for (int m = 1; m < 64; m <<= 1) s += __shfl_xor(s, m);
    if (lane == 0 && e < E) out[e] = s + b2[0];
}

extern "C" void kernel_launch(void* const* d_in, const int* in_sizes, int n_in,
                              void* d_out, int out_size, void* d_ws, size_t ws_size,
                              hipStream_t stream) {
    const float* zs = (const float*)d_in[0];
    const float* zt = (const float*)d_in[1];
    const int*  row = (const int*)d_in[2];
    const int*  col = (const int*)d_in[3];
    const float* W1 = (const float*)d_in[4];
    const float* b1 = (const float*)d_in[5];
    const float* W2 = (const float*)d_in[6];
    const float* b2 = (const float*)d_in[7];
    float* out = (float*)d_out;

    const int nzs = in_sizes[0];       // 12,800,000 (100K x 128)
    const int nzt = in_sizes[1];       // 6,400,000  (50K x 128)
    const int E   = in_sizes[2];       // 1,000,000
    const int M1  = nzs / 128;
    const int M2  = nzt / 128;

    const size_t need = ((size_t)nzs + (size_t)nzt + 32768) * 2;
    if (ws_size < need) {
        int nb = (E + 3) / 4;
        edge_mlp_naive<<<nb, 256, 0, stream>>>(zs, zt, row, col, W1, b1, W2, b2, out, E);
        return;
    }

    u16* U   = (u16*)d_ws;             // M1 x 128 fp16
    u16* V   = U + (size_t)nzs;        // M2 x 128 fp16
    u16* w1p = V + (size_t)nzt;        // 64 KB packed W1 (bf16 frags)

    w1_pack<<<16, 256, 0, stream>>>(W1, w1p);

    const int nU = (M1 + 63) / 64;
    const int nV = (M2 + 63) / 64;
    uv_gemm<<<nU + nV, 256, 0, stream>>>(zs, zt, w1p, b1, U, V, M1, M2, nU);

    edge_out<<<(E + 127) / 128, 256, 0, stream>>>(U, V, row, col, W2, b2, out, E);
}